// Round 1
// baseline (3047.649 us; speedup 1.0000x reference)
//
#include <hip/hip_runtime.h>

#define NF 128
#define NH 128
#define NO 256
#define NG 256

// ---------------- degree / norm precompute ----------------

__global__ void deg_kernel(const int* __restrict__ col, int E, float* __restrict__ deg) {
    int e = blockIdx.x * blockDim.x + threadIdx.x;
    if (e < E) atomicAdd(&deg[col[e]], 1.0f);
}

__global__ void dinv_kernel(float* __restrict__ deg, int n) {
    int i = blockIdx.x * blockDim.x + threadIdx.x;
    if (i < n) deg[i] = rsqrtf(deg[i] + 1.0f);   // +1 for self loop
}

__global__ void norm_kernel(const int* __restrict__ row, const int* __restrict__ col,
                            const float* __restrict__ dinv, float* __restrict__ normv, int E) {
    int e = blockIdx.x * blockDim.x + threadIdx.x;
    if (e < E) normv[e] = dinv[row[e]] * dinv[col[e]];
}

// ---------------- dense transform: C[n x 128] = A[n x 128] @ W[128 x 128] ----------------
// W staged fully in LDS (64 KB). 256 threads: thread -> (srow = tid/32 in 0..7, c4 = (tid&31)*4).
// Each thread computes 4 output cols for 1 node; 8 nodes per block.

__global__ __launch_bounds__(256) void gemm_nodes(const float* __restrict__ A,
                                                  const float* __restrict__ W,
                                                  float* __restrict__ C, int n) {
    __shared__ float Ws[NF * NH];   // W[k][j], k-major (row-major as given)
    __shared__ float xs[8][NF];
    int tid = threadIdx.x;
    for (int i = tid; i < NF * NH; i += 256) Ws[i] = W[i];

    int srow = tid >> 5;            // 0..7  node within block
    int c4   = (tid & 31) * 4;      // output col group
    int node = blockIdx.x * 8 + srow;

    // cooperative load of 8 x-rows (each thread loads one float4)
    if (node < n) {
        const float4* arow = (const float4*)(A + (size_t)node * NF);
        float4 v = arow[tid & 31];
        xs[srow][c4 + 0] = v.x; xs[srow][c4 + 1] = v.y;
        xs[srow][c4 + 2] = v.z; xs[srow][c4 + 3] = v.w;
    }
    __syncthreads();
    if (node >= n) return;

    float4 acc = make_float4(0.f, 0.f, 0.f, 0.f);
    #pragma unroll 8
    for (int k = 0; k < NF; ++k) {
        float4 w = *(const float4*)&Ws[k * NH + c4];
        float  x = xs[srow][k];
        acc.x += x * w.x; acc.y += x * w.y; acc.z += x * w.z; acc.w += x * w.w;
    }
    *(float4*)(C + (size_t)node * NH + c4) = acc;
}

// ---------------- edge scatter: out[col] += norm * tmp[row] ----------------
// one thread per (edge, feature)

__global__ __launch_bounds__(256) void scatter_kernel(const int* __restrict__ row,
                                                      const int* __restrict__ col,
                                                      const float* __restrict__ normv,
                                                      const float* __restrict__ tmp,
                                                      float* __restrict__ out, int E) {
    int idx = blockIdx.x * 256 + threadIdx.x;
    int e = idx >> 7;
    int j = idx & 127;
    if (e < E) {
        int r = row[e], c = col[e];
        float v = normv[e] * tmp[(size_t)r * NH + j];
        atomicAdd(&out[(size_t)c * NH + j], v);
    }
}

// ---------------- self loop + bias + relu ----------------

__global__ __launch_bounds__(256) void selfloop_bias_relu(const float* __restrict__ tmp,
                                                          const float* __restrict__ dinv,
                                                          const float* __restrict__ b,
                                                          float* __restrict__ out, int n) {
    int idx = blockIdx.x * 256 + threadIdx.x;
    int i = idx >> 7;
    int j = idx & 127;
    if (i < n) {
        float di = dinv[i];
        float v = out[idx] + di * di * tmp[idx] + b[j];
        out[idx] = fmaxf(v, 0.f);
    }
}

// ---------------- mean pool (atomic accumulate) ----------------

__global__ __launch_bounds__(256) void pool_kernel(const float* __restrict__ h,
                                                   const int* __restrict__ batch,
                                                   float* __restrict__ pooled,
                                                   float* __restrict__ cnt, int n) {
    int idx = blockIdx.x * 256 + threadIdx.x;
    int i = idx >> 7;
    int j = idx & 127;
    if (i < n) {
        int g = batch[i];
        atomicAdd(&pooled[(size_t)g * NH + j], h[idx]);
        if (j == 0) atomicAdd(&cnt[g], 1.0f);
    }
}

// ---------------- final FC: out[g] = (pooled[g]/cnt[g]) @ Wfc + bfc ----------------

__global__ __launch_bounds__(256) void final_fc(const float* __restrict__ pooled,
                                                const float* __restrict__ cnt,
                                                const float* __restrict__ Wfc,
                                                const float* __restrict__ bfc,
                                                float* __restrict__ out) {
    int g = blockIdx.x;
    int j = threadIdx.x;              // 0..255 output col
    __shared__ float pr[NH];
    float inv = 1.0f / fmaxf(cnt[g], 1.0f);
    if (j < NH) pr[j] = pooled[(size_t)g * NH + j] * inv;
    __syncthreads();
    float acc = bfc[j];
    #pragma unroll 8
    for (int k = 0; k < NH; ++k) acc += pr[k] * Wfc[(size_t)k * NO + j];
    out[(size_t)g * NO + j] = acc;
}

// ---------------- launch ----------------

extern "C" void kernel_launch(void* const* d_in, const int* in_sizes, int n_in,
                              void* d_out, int out_size, void* d_ws, size_t ws_size,
                              hipStream_t stream) {
    const float* x   = (const float*)d_in[0];
    const float* W1  = (const float*)d_in[1];
    const float* b1  = (const float*)d_in[2];
    const float* W2  = (const float*)d_in[3];
    const float* b2  = (const float*)d_in[4];
    const float* W3  = (const float*)d_in[5];
    const float* b3  = (const float*)d_in[6];
    const float* Wfc = (const float*)d_in[7];
    const float* bfc = (const float*)d_in[8];
    const int*   ei  = (const int*)d_in[9];    // [2, E] flat
    const int*   bat = (const int*)d_in[10];   // [N]
    float* out = (float*)d_out;

    const int N = in_sizes[0] / NF;
    const int E = in_sizes[9] / 2;
    const int* rowp = ei;
    const int* colp = ei + E;

    // workspace layout (floats)
    float* buf0   = (float*)d_ws;                       // N*NH  (gemm tmp)
    float* buf1   = buf0 + (size_t)N * NH;              // N*NH  (node state)
    float* dinv   = buf1 + (size_t)N * NH;              // N
    float* normv  = dinv + N;                           // E
    float* pooled = normv + E;                          // NG*NH
    float* cnt    = pooled + (size_t)NG * NH;           // NG

    const int TB = 256;
    int gE   = (E + TB - 1) / TB;
    int gN   = (N + TB - 1) / TB;
    int gNF  = ((size_t)N * NH + TB - 1) / TB;
    int gEF  = ((int)(((size_t)E * NH + TB - 1) / TB));
    int gGemm = (N + 7) / 8;

    // degree -> dinv -> per-edge norm
    hipMemsetAsync(dinv, 0, (size_t)N * sizeof(float), stream);
    deg_kernel<<<gE, TB, 0, stream>>>(colp, E, dinv);
    dinv_kernel<<<gN, TB, 0, stream>>>(dinv, N);
    norm_kernel<<<gE, TB, 0, stream>>>(rowp, colp, dinv, normv, E);

    // ---- layer 1 ----
    gemm_nodes<<<gGemm, TB, 0, stream>>>(x, W1, buf0, N);
    hipMemsetAsync(buf1, 0, (size_t)N * NH * sizeof(float), stream);
    scatter_kernel<<<gEF, TB, 0, stream>>>(rowp, colp, normv, buf0, buf1, E);
    selfloop_bias_relu<<<gNF, TB, 0, stream>>>(buf0, dinv, b1, buf1, N);

    // ---- layer 2 ----
    gemm_nodes<<<gGemm, TB, 0, stream>>>(buf1, W2, buf0, N);
    hipMemsetAsync(buf1, 0, (size_t)N * NH * sizeof(float), stream);
    scatter_kernel<<<gEF, TB, 0, stream>>>(rowp, colp, normv, buf0, buf1, E);
    selfloop_bias_relu<<<gNF, TB, 0, stream>>>(buf0, dinv, b2, buf1, N);

    // ---- layer 3 ----
    gemm_nodes<<<gGemm, TB, 0, stream>>>(buf1, W3, buf0, N);
    hipMemsetAsync(buf1, 0, (size_t)N * NH * sizeof(float), stream);
    scatter_kernel<<<gEF, TB, 0, stream>>>(rowp, colp, normv, buf0, buf1, E);
    selfloop_bias_relu<<<gNF, TB, 0, stream>>>(buf0, dinv, b3, buf1, N);

    // ---- pool + fc ----
    hipMemsetAsync(pooled, 0, (size_t)(NG * NH + NG) * sizeof(float), stream);
    pool_kernel<<<gNF, TB, 0, stream>>>(buf1, bat, pooled, cnt, N);
    final_fc<<<NG, NO, 0, stream>>>(pooled, cnt, Wfc, bfc, out);
}

// Round 2
// 1927.421 us; speedup vs baseline: 1.5812x; 1.5812x over previous
//
#include <hip/hip_runtime.h>

#define NF 128
#define NH 128
#define NO 256
#define NG 256

// ---------------- CSR build: histogram, scan, bucket ----------------

__global__ void hist_kernel(const int* __restrict__ col, int E, int* __restrict__ deg) {
    int e = blockIdx.x * blockDim.x + threadIdx.x;
    if (e < E) atomicAdd(&deg[col[e]], 1);
}

__global__ void dinv_kernel(const int* __restrict__ deg, float* __restrict__ dinv, int n) {
    int i = blockIdx.x * blockDim.x + threadIdx.x;
    if (i < n) dinv[i] = rsqrtf((float)deg[i] + 1.0f);   // +1 for self loop
}

// exclusive scan, 2-level (256/block; numBlocks <= 512)
__global__ void scan1(const int* __restrict__ deg, int n, int* __restrict__ offs,
                      int* __restrict__ partials) {
    __shared__ int sh[256];
    int tid = threadIdx.x;
    int i = blockIdx.x * 256 + tid;
    int v = (i < n) ? deg[i] : 0;
    sh[tid] = v; __syncthreads();
    for (int d = 1; d < 256; d <<= 1) {
        int t = (tid >= d) ? sh[tid - d] : 0;
        __syncthreads();
        sh[tid] += t;
        __syncthreads();
    }
    if (i < n) offs[i] = sh[tid] - v;          // exclusive within block
    if (tid == 255) partials[blockIdx.x] = sh[255];
}

__global__ void scan2(int* __restrict__ partials, int nb) {
    __shared__ int sh[512];
    int tid = threadIdx.x;
    int v = (tid < nb) ? partials[tid] : 0;
    sh[tid] = v; __syncthreads();
    for (int d = 1; d < 512; d <<= 1) {
        int t = (tid >= d) ? sh[tid - d] : 0;
        __syncthreads();
        sh[tid] += t;
        __syncthreads();
    }
    if (tid < nb) partials[tid] = sh[tid] - v; // exclusive
}

__global__ void scan3(int* __restrict__ offs, const int* __restrict__ partials, int n) {
    int i = blockIdx.x * blockDim.x + threadIdx.x;
    if (i < n) offs[i] += partials[i >> 8];
}

__global__ void build_csr(const int* __restrict__ row, const int* __restrict__ col,
                          const float* __restrict__ dinv, const int* __restrict__ offs,
                          int* __restrict__ cursor, int* __restrict__ srcs,
                          float* __restrict__ norms, int E) {
    int e = blockIdx.x * blockDim.x + threadIdx.x;
    if (e < E) {
        int c = col[e];
        int p = offs[c] + atomicAdd(&cursor[c], 1);
        int r = row[e];
        srcs[p] = r;
        norms[p] = dinv[r] * dinv[c];
    }
}

// ---------------- dense transform: C[n x 128] = A[n x 128] @ W[128 x 128] ----------------

__global__ __launch_bounds__(256) void gemm_nodes(const float* __restrict__ A,
                                                  const float* __restrict__ W,
                                                  float* __restrict__ C, int n) {
    __shared__ float Ws[NF * NH];   // W[k][j], k-major
    __shared__ float xs[8][NF];
    int tid = threadIdx.x;
    for (int i = tid; i < NF * NH; i += 256) Ws[i] = W[i];

    int srow = tid >> 5;            // 0..7  node within block
    int c4   = (tid & 31) * 4;      // output col group
    int node = blockIdx.x * 8 + srow;

    if (node < n) {
        const float4* arow = (const float4*)(A + (size_t)node * NF);
        float4 v = arow[tid & 31];
        xs[srow][c4 + 0] = v.x; xs[srow][c4 + 1] = v.y;
        xs[srow][c4 + 2] = v.z; xs[srow][c4 + 3] = v.w;
    }
    __syncthreads();
    if (node >= n) return;

    float4 acc = make_float4(0.f, 0.f, 0.f, 0.f);
    #pragma unroll 8
    for (int k = 0; k < NF; ++k) {
        float4 w = *(const float4*)&Ws[k * NH + c4];
        float  x = xs[srow][k];
        acc.x += x * w.x; acc.y += x * w.y; acc.z += x * w.z; acc.w += x * w.w;
    }
    *(float4*)(C + (size_t)node * NH + c4) = acc;
}

// ---------------- fused CSR aggregate + self-loop + bias + relu ----------------
// 2 nodes per 256-thread block; thread j of a 128-lane group = feature j.

__global__ __launch_bounds__(256) void gcn_aggregate(const float* __restrict__ tmp,
                                                     const int* __restrict__ srcs,
                                                     const float* __restrict__ norms,
                                                     const int* __restrict__ offs,
                                                     const int* __restrict__ deg,
                                                     const float* __restrict__ dinv,
                                                     const float* __restrict__ bias,
                                                     float* __restrict__ out, int n) {
    int node = blockIdx.x * 2 + (threadIdx.x >> 7);
    int j = threadIdx.x & 127;
    if (node >= n) return;
    int start = offs[node];
    int end   = start + deg[node];
    float acc = 0.f;
    for (int k = start; k < end; ++k) {
        int   s  = srcs[k];
        float nv = norms[k];
        acc += nv * tmp[(size_t)s * NH + j];
    }
    float di = dinv[node];
    acc += di * di * tmp[(size_t)node * NH + j] + bias[j];
    out[(size_t)node * NH + j] = fmaxf(acc, 0.f);
}

// ---------------- mean pool (atomic accumulate) ----------------

__global__ __launch_bounds__(256) void pool_kernel(const float* __restrict__ h,
                                                   const int* __restrict__ batch,
                                                   float* __restrict__ pooled,
                                                   float* __restrict__ cnt, int n) {
    int idx = blockIdx.x * 256 + threadIdx.x;
    int i = idx >> 7;
    int j = idx & 127;
    if (i < n) {
        int g = batch[i];
        atomicAdd(&pooled[(size_t)g * NH + j], h[idx]);
        if (j == 0) atomicAdd(&cnt[g], 1.0f);
    }
}

// ---------------- final FC ----------------

__global__ __launch_bounds__(256) void final_fc(const float* __restrict__ pooled,
                                                const float* __restrict__ cnt,
                                                const float* __restrict__ Wfc,
                                                const float* __restrict__ bfc,
                                                float* __restrict__ out) {
    int g = blockIdx.x;
    int j = threadIdx.x;
    __shared__ float pr[NH];
    float inv = 1.0f / fmaxf(cnt[g], 1.0f);
    if (j < NH) pr[j] = pooled[(size_t)g * NH + j] * inv;
    __syncthreads();
    float acc = bfc[j];
    #pragma unroll 8
    for (int k = 0; k < NH; ++k) acc += pr[k] * Wfc[(size_t)k * NO + j];
    out[(size_t)g * NO + j] = acc;
}

// ---------------- launch ----------------

extern "C" void kernel_launch(void* const* d_in, const int* in_sizes, int n_in,
                              void* d_out, int out_size, void* d_ws, size_t ws_size,
                              hipStream_t stream) {
    const float* x   = (const float*)d_in[0];
    const float* W1  = (const float*)d_in[1];
    const float* b1  = (const float*)d_in[2];
    const float* W2  = (const float*)d_in[3];
    const float* b2  = (const float*)d_in[4];
    const float* W3  = (const float*)d_in[5];
    const float* b3  = (const float*)d_in[6];
    const float* Wfc = (const float*)d_in[7];
    const float* bfc = (const float*)d_in[8];
    const int*   ei  = (const int*)d_in[9];    // [2, E] flat
    const int*   bat = (const int*)d_in[10];   // [N]
    float* out = (float*)d_out;

    const int N = in_sizes[0] / NF;
    const int E = in_sizes[9] / 2;
    const int* rowp = ei;
    const int* colp = ei + E;

    // workspace layout
    float* buf0   = (float*)d_ws;                       // N*NH
    float* buf1   = buf0 + (size_t)N * NH;              // N*NH
    float* dinv   = buf1 + (size_t)N * NH;              // N
    float* norms  = dinv + N;                           // E
    float* pooled = norms + E;                          // NG*NH
    float* cnt    = pooled + (size_t)NG * NH;           // NG
    int*   degc   = (int*)(cnt + NG);                   // N
    int*   offs   = degc + N;                           // N
    int*   cursor = offs + N;                           // N
    int*   partials = cursor + N;                       // 512
    int*   srcs   = partials + 512;                     // E

    const int TB = 256;
    int gE   = (E + TB - 1) / TB;
    int gN   = (N + TB - 1) / TB;
    int gNF  = (int)(((size_t)N * NH + TB - 1) / TB);
    int gGemm = (N + 7) / 8;
    int gAgg  = (N + 1) / 2;
    int nScanBlocks = (N + 255) / 256;   // must be <= 512

    // ---- CSR build ----
    hipMemsetAsync(degc, 0, 2 * (size_t)N * sizeof(int), stream);   // degc + cursor... (separate below)
    hipMemsetAsync(cursor, 0, (size_t)N * sizeof(int), stream);
    hist_kernel<<<gE, TB, 0, stream>>>(colp, E, degc);
    dinv_kernel<<<gN, TB, 0, stream>>>(degc, dinv, N);
    scan1<<<nScanBlocks, 256, 0, stream>>>(degc, N, offs, partials);
    scan2<<<1, 512, 0, stream>>>(partials, nScanBlocks);
    scan3<<<gN, TB, 0, stream>>>(offs, partials, N);
    build_csr<<<gE, TB, 0, stream>>>(rowp, colp, dinv, offs, cursor, srcs, norms, E);

    // ---- layer 1 ----
    gemm_nodes<<<gGemm, TB, 0, stream>>>(x, W1, buf0, N);
    gcn_aggregate<<<gAgg, TB, 0, stream>>>(buf0, srcs, norms, offs, degc, dinv, b1, buf1, N);

    // ---- layer 2 ----
    gemm_nodes<<<gGemm, TB, 0, stream>>>(buf1, W2, buf0, N);
    gcn_aggregate<<<gAgg, TB, 0, stream>>>(buf0, srcs, norms, offs, degc, dinv, b2, buf1, N);

    // ---- layer 3 ----
    gemm_nodes<<<gGemm, TB, 0, stream>>>(buf1, W3, buf0, N);
    gcn_aggregate<<<gAgg, TB, 0, stream>>>(buf0, srcs, norms, offs, degc, dinv, b3, buf1, N);

    // ---- pool + fc ----
    hipMemsetAsync(pooled, 0, (size_t)(NG * NH + NG) * sizeof(float), stream);
    pool_kernel<<<gNF, TB, 0, stream>>>(buf1, bat, pooled, cnt, N);
    final_fc<<<NG, NO, 0, stream>>>(pooled, cnt, Wfc, bfc, out);
}

// Round 3
// 1542.529 us; speedup vs baseline: 1.9757x; 1.2495x over previous
//
#include <hip/hip_runtime.h>

#define NF 128
#define NH 128
#define NO 256
#define NG 256

// ---------------- CSR build: histogram, scan, bucket ----------------

__global__ void hist_kernel(const int* __restrict__ col, int E, int* __restrict__ deg) {
    int e = blockIdx.x * blockDim.x + threadIdx.x;
    if (e < E) atomicAdd(&deg[col[e]], 1);
}

__global__ void dinv_kernel(const int* __restrict__ deg, float* __restrict__ dinv, int n) {
    int i = blockIdx.x * blockDim.x + threadIdx.x;
    if (i < n) dinv[i] = rsqrtf((float)deg[i] + 1.0f);   // +1 for self loop
}

// exclusive scan, 2-level (256/block; numBlocks <= 512)
__global__ void scan1(const int* __restrict__ deg, int n, int* __restrict__ offs,
                      int* __restrict__ partials) {
    __shared__ int sh[256];
    int tid = threadIdx.x;
    int i = blockIdx.x * 256 + tid;
    int v = (i < n) ? deg[i] : 0;
    sh[tid] = v; __syncthreads();
    for (int d = 1; d < 256; d <<= 1) {
        int t = (tid >= d) ? sh[tid - d] : 0;
        __syncthreads();
        sh[tid] += t;
        __syncthreads();
    }
    if (i < n) offs[i] = sh[tid] - v;          // exclusive within block
    if (tid == 255) partials[blockIdx.x] = sh[255];
}

__global__ void scan2(int* __restrict__ partials, int nb) {
    __shared__ int sh[512];
    int tid = threadIdx.x;
    int v = (tid < nb) ? partials[tid] : 0;
    sh[tid] = v; __syncthreads();
    for (int d = 1; d < 512; d <<= 1) {
        int t = (tid >= d) ? sh[tid - d] : 0;
        __syncthreads();
        sh[tid] += t;
        __syncthreads();
    }
    if (tid < nb) partials[tid] = sh[tid] - v; // exclusive
}

__global__ void scan3(int* __restrict__ offs, const int* __restrict__ partials, int n) {
    int i = blockIdx.x * blockDim.x + threadIdx.x;
    if (i < n) offs[i] += partials[i >> 8];
}

__global__ void build_csr(const int* __restrict__ row, const int* __restrict__ col,
                          const float* __restrict__ dinv, const int* __restrict__ offs,
                          int* __restrict__ cursor, int* __restrict__ srcs,
                          float* __restrict__ norms, int E) {
    int e = blockIdx.x * blockDim.x + threadIdx.x;
    if (e < E) {
        int c = col[e];
        int p = offs[c] + atomicAdd(&cursor[c], 1);
        int r = row[e];
        srcs[p] = r;
        norms[p] = dinv[r] * dinv[c];
    }
}

// ---------------- dense transform: C[n x 128] = A[n x 128] @ W[128 x 128] ----------------

__global__ __launch_bounds__(256) void gemm_nodes(const float* __restrict__ A,
                                                  const float* __restrict__ W,
                                                  float* __restrict__ C, int n) {
    __shared__ float Ws[NF * NH];   // W[k][j], k-major
    __shared__ float xs[8][NF];
    int tid = threadIdx.x;
    for (int i = tid; i < NF * NH; i += 256) Ws[i] = W[i];

    int srow = tid >> 5;            // 0..7  node within block
    int c4   = (tid & 31) * 4;      // output col group
    int node = blockIdx.x * 8 + srow;

    if (node < n) {
        const float4* arow = (const float4*)(A + (size_t)node * NF);
        float4 v = arow[tid & 31];
        xs[srow][c4 + 0] = v.x; xs[srow][c4 + 1] = v.y;
        xs[srow][c4 + 2] = v.z; xs[srow][c4 + 3] = v.w;
    }
    __syncthreads();
    if (node >= n) return;

    float4 acc = make_float4(0.f, 0.f, 0.f, 0.f);
    #pragma unroll 8
    for (int k = 0; k < NF; ++k) {
        float4 w = *(const float4*)&Ws[k * NH + c4];
        float  x = xs[srow][k];
        acc.x += x * w.x; acc.y += x * w.y; acc.z += x * w.z; acc.w += x * w.w;
    }
    *(float4*)(C + (size_t)node * NH + c4) = acc;
}

// ---------------- fused CSR aggregate + self-loop + bias + relu ----------------
// 2 nodes per 256-thread block; thread j of a 128-lane group = feature j.

__global__ __launch_bounds__(256) void gcn_aggregate(const float* __restrict__ tmp,
                                                     const int* __restrict__ srcs,
                                                     const float* __restrict__ norms,
                                                     const int* __restrict__ offs,
                                                     const int* __restrict__ deg,
                                                     const float* __restrict__ dinv,
                                                     const float* __restrict__ bias,
                                                     float* __restrict__ out, int n) {
    int node = blockIdx.x * 2 + (threadIdx.x >> 7);
    int j = threadIdx.x & 127;
    if (node >= n) return;
    int start = offs[node];
    int end   = start + deg[node];
    float acc = 0.f;
    for (int k = start; k < end; ++k) {
        int   s  = srcs[k];
        float nv = norms[k];
        acc += nv * tmp[(size_t)s * NH + j];
    }
    float di = dinv[node];
    acc += di * di * tmp[(size_t)node * NH + j] + bias[j];
    out[(size_t)node * NH + j] = fmaxf(acc, 0.f);
}

// ---------------- fused mean-pool + final FC ----------------
// one block per graph; batch[] is sorted, so binary-search the node range,
// accumulate the segment sum in registers (no atomics), then matvec with Wfc.

__global__ __launch_bounds__(256) void pool_fc(const float* __restrict__ h,
                                               const int* __restrict__ batch,
                                               const float* __restrict__ Wfc,
                                               const float* __restrict__ bfc,
                                               float* __restrict__ out, int n) {
    int g = blockIdx.x;
    int tid = threadIdx.x;
    int j = tid & 127;
    int half = tid >> 7;   // 0 or 1

    // lower_bound(batch, g) and lower_bound(batch, g+1)
    int lo = 0, hi = n;
    while (lo < hi) { int m = (lo + hi) >> 1; if (batch[m] < g) lo = m + 1; else hi = m; }
    int start = lo;
    hi = n;
    while (lo < hi) { int m = (lo + hi) >> 1; if (batch[m] < g + 1) lo = m + 1; else hi = m; }
    int end = lo;

    float acc = 0.f;
    for (int i = start + half; i < end; i += 2)
        acc += h[(size_t)i * NH + j];

    __shared__ float sum[NH];
    __shared__ float pr[NH];
    if (half == 0) sum[j] = acc;
    __syncthreads();
    if (half == 1) sum[j] += acc;
    __syncthreads();
    float inv = 1.0f / fmaxf((float)(end - start), 1.0f);
    if (half == 0) pr[j] = sum[j] * inv;
    __syncthreads();

    // FC: each of 256 threads computes one output col
    float o = bfc[tid];
    #pragma unroll 8
    for (int k = 0; k < NH; ++k) o += pr[k] * Wfc[(size_t)k * NO + tid];
    out[(size_t)g * NO + tid] = o;
}

// ---------------- launch ----------------

extern "C" void kernel_launch(void* const* d_in, const int* in_sizes, int n_in,
                              void* d_out, int out_size, void* d_ws, size_t ws_size,
                              hipStream_t stream) {
    const float* x   = (const float*)d_in[0];
    const float* W1  = (const float*)d_in[1];
    const float* b1  = (const float*)d_in[2];
    const float* W2  = (const float*)d_in[3];
    const float* b2  = (const float*)d_in[4];
    const float* W3  = (const float*)d_in[5];
    const float* b3  = (const float*)d_in[6];
    const float* Wfc = (const float*)d_in[7];
    const float* bfc = (const float*)d_in[8];
    const int*   ei  = (const int*)d_in[9];    // [2, E] flat
    const int*   bat = (const int*)d_in[10];   // [N]
    float* out = (float*)d_out;

    const int N = in_sizes[0] / NF;
    const int E = in_sizes[9] / 2;
    const int* rowp = ei;
    const int* colp = ei + E;

    // workspace layout
    float* buf0   = (float*)d_ws;                       // N*NH
    float* buf1   = buf0 + (size_t)N * NH;              // N*NH
    float* dinv   = buf1 + (size_t)N * NH;              // N
    float* norms  = dinv + N;                           // E
    int*   degc   = (int*)(norms + E);                  // N
    int*   offs   = degc + N;                           // N
    int*   cursor = offs + N;                           // N
    int*   partials = cursor + N;                       // 512
    int*   srcs   = partials + 512;                     // E

    const int TB = 256;
    int gE   = (E + TB - 1) / TB;
    int gN   = (N + TB - 1) / TB;
    int gGemm = (N + 7) / 8;
    int gAgg  = (N + 1) / 2;
    int nScanBlocks = (N + 255) / 256;   // must be <= 512

    // ---- CSR build ----
    hipMemsetAsync(degc, 0, (size_t)N * sizeof(int), stream);
    hipMemsetAsync(cursor, 0, (size_t)N * sizeof(int), stream);
    hist_kernel<<<gE, TB, 0, stream>>>(colp, E, degc);
    dinv_kernel<<<gN, TB, 0, stream>>>(degc, dinv, N);
    scan1<<<nScanBlocks, 256, 0, stream>>>(degc, N, offs, partials);
    scan2<<<1, 512, 0, stream>>>(partials, nScanBlocks);
    scan3<<<gN, TB, 0, stream>>>(offs, partials, N);
    build_csr<<<gE, TB, 0, stream>>>(rowp, colp, dinv, offs, cursor, srcs, norms, E);

    // ---- layer 1 ----
    gemm_nodes<<<gGemm, TB, 0, stream>>>(x, W1, buf0, N);
    gcn_aggregate<<<gAgg, TB, 0, stream>>>(buf0, srcs, norms, offs, degc, dinv, b1, buf1, N);

    // ---- layer 2 ----
    gemm_nodes<<<gGemm, TB, 0, stream>>>(buf1, W2, buf0, N);
    gcn_aggregate<<<gAgg, TB, 0, stream>>>(buf0, srcs, norms, offs, degc, dinv, b2, buf1, N);

    // ---- layer 3 ----
    gemm_nodes<<<gGemm, TB, 0, stream>>>(buf1, W3, buf0, N);
    gcn_aggregate<<<gAgg, TB, 0, stream>>>(buf0, srcs, norms, offs, degc, dinv, b3, buf1, N);

    // ---- fused pool + fc ----
    pool_fc<<<NG, 256, 0, stream>>>(buf1, bat, Wfc, bfc, out, N);
}

// Round 5
// 613.630 us; speedup vs baseline: 4.9666x; 2.5138x over previous
//
#include <hip/hip_runtime.h>

#define NF 128
#define NH 128
#define NO 256
#define NG 256

typedef unsigned int   u32;
typedef unsigned short u16;
typedef __attribute__((ext_vector_type(8))) short short8;
typedef __attribute__((ext_vector_type(4))) float floatx4;

__device__ __forceinline__ float bflo(u32 g) { return __uint_as_float(g << 16); }
__device__ __forceinline__ float bfhi(u32 g) { return __uint_as_float(g & 0xffff0000u); }
__device__ __forceinline__ u16 f2bf(float x) {
    u32 u = __float_as_uint(x);
    u += 0x7fffu + ((u >> 16) & 1u);
    return (u16)(u >> 16);
}
__device__ __forceinline__ u32 packbf2(float x, float y) {
    u32 ux = __float_as_uint(x); ux += 0x7fffu + ((ux >> 16) & 1u);
    u32 uy = __float_as_uint(y); uy += 0x7fffu + ((uy >> 16) & 1u);
    return (ux >> 16) | (uy & 0xffff0000u);
}

// ---------------- CSR build ----------------

__global__ void hist_kernel(const int* __restrict__ col, int E, int* __restrict__ deg) {
    int e = blockIdx.x * blockDim.x + threadIdx.x;
    if (e < E) atomicAdd(&deg[col[e]], 1);
}

__global__ void dinv_kernel(const int* __restrict__ deg, float* __restrict__ dinv, int n) {
    int i = blockIdx.x * blockDim.x + threadIdx.x;
    if (i < n) dinv[i] = rsqrtf((float)deg[i] + 1.0f);
}

__global__ void scan1(const int* __restrict__ deg, int n, int* __restrict__ offs,
                      int* __restrict__ partials) {
    __shared__ int sh[256];
    int tid = threadIdx.x;
    int i = blockIdx.x * 256 + tid;
    int v = (i < n) ? deg[i] : 0;
    sh[tid] = v; __syncthreads();
    for (int d = 1; d < 256; d <<= 1) {
        int t = (tid >= d) ? sh[tid - d] : 0;
        __syncthreads();
        sh[tid] += t;
        __syncthreads();
    }
    if (i < n) offs[i] = sh[tid] - v;
    if (tid == 255) partials[blockIdx.x] = sh[255];
}

__global__ void scan2(int* __restrict__ partials, int nb) {
    __shared__ int sh[512];
    int tid = threadIdx.x;
    int v = (tid < nb) ? partials[tid] : 0;
    sh[tid] = v; __syncthreads();
    for (int d = 1; d < 512; d <<= 1) {
        int t = (tid >= d) ? sh[tid - d] : 0;
        __syncthreads();
        sh[tid] += t;
        __syncthreads();
    }
    if (tid < nb) partials[tid] = sh[tid] - v;
}

__global__ void scan3(int* __restrict__ offs, const int* __restrict__ partials, int n) {
    int i = blockIdx.x * blockDim.x + threadIdx.x;
    if (i < n) offs[i] += partials[i >> 8];
}

__global__ void build_csr(const int* __restrict__ row, const int* __restrict__ col,
                          const float* __restrict__ dinv, const int* __restrict__ offs,
                          int* __restrict__ cursor, uint2* __restrict__ edges, int E) {
    int e = blockIdx.x * blockDim.x + threadIdx.x;
    if (e < E) {
        int c = col[e];
        int p = offs[c] + atomicAdd(&cursor[c], 1);
        int r = row[e];
        uint2 v; v.x = (u32)r; v.y = __float_as_uint(dinv[r] * dinv[c]);
        edges[p] = v;
    }
}

// ---------------- casts ----------------

__global__ void cast_x_kernel(const float* __restrict__ x, u16* __restrict__ xb, long total4) {
    long i = (long)blockIdx.x * 256 + threadIdx.x;
    if (i < total4) {
        float4 v = ((const float4*)x)[i];
        ushort4 o; o.x = f2bf(v.x); o.y = f2bf(v.y); o.z = f2bf(v.z); o.w = f2bf(v.w);
        ((ushort4*)xb)[i] = o;
    }
}

// W[k][col] f32 -> Wt[col][k] bf16 (128x128)
__global__ void cast_w_t(const float* __restrict__ W, u16* __restrict__ Wt) {
    int idx = blockIdx.x * 256 + threadIdx.x;
    int k = idx >> 7, c = idx & 127;
    Wt[c * NF + k] = f2bf(W[idx]);
}

// ---------------- MFMA GEMM: C[n x 128] = A[n x 128] @ W[128 x 128], bf16 in/out ----------------
// 64 nodes/block, 256 thr = 4 waves; wave handles 16 nodes x 128 cols.
// LDS: As[64][136] bf16, Wt[128][136] bf16 (reused as Cs[64][132] f32 in epilogue).

__global__ __launch_bounds__(256) void gemm_mfma(const u16* __restrict__ A,
                                                 const u16* __restrict__ Wtg,
                                                 u16* __restrict__ C, int n) {
    __shared__ u16 As[64 * 136];
    __shared__ u16 Wt[128 * 136];
    int t = threadIdx.x;
    int node0 = blockIdx.x * 64;

    // stage A tile (64 rows x 16 uint4)
    const uint4* Ag = (const uint4*)A;
    #pragma unroll
    for (int i = 0; i < 4; ++i) {
        int idx = t + 256 * i;
        int nd = idx >> 4, q = idx & 15;
        uint4 v = make_uint4(0, 0, 0, 0);
        if (node0 + nd < n) v = Ag[(size_t)(node0 + nd) * 16 + q];
        *(uint4*)&As[nd * 136 + q * 8] = v;
    }
    // stage Wt (128 rows x 16 uint4)
    const uint4* Wg = (const uint4*)Wtg;
    #pragma unroll
    for (int i = 0; i < 8; ++i) {
        int idx = t + 256 * i;
        int cc = idx >> 4, q = idx & 15;
        *(uint4*)&Wt[cc * 136 + q * 8] = Wg[cc * 16 + q];
    }
    __syncthreads();

    int wv = t >> 6;
    int l  = t & 63;
    int lr = l & 15;
    int lq = l >> 4;

    floatx4 acc[8];
    #pragma unroll
    for (int c = 0; c < 8; ++c) acc[c] = (floatx4){0.f, 0.f, 0.f, 0.f};

    #pragma unroll
    for (int kk = 0; kk < 4; ++kk) {
        short8 af = *(const short8*)&As[(wv * 16 + lr) * 136 + kk * 32 + lq * 8];
        #pragma unroll
        for (int c = 0; c < 8; ++c) {
            short8 bf = *(const short8*)&Wt[(c * 16 + lr) * 136 + kk * 32 + lq * 8];
            acc[c] = __builtin_amdgcn_mfma_f32_16x16x32_bf16(af, bf, acc[c], 0, 0, 0);
        }
    }
    __syncthreads();   // all waves done reading Wt before reuse as Cs

    float* Cs = (float*)Wt;   // 64 x 132 f32
    #pragma unroll
    for (int c = 0; c < 8; ++c)
        #pragma unroll
        for (int r = 0; r < 4; ++r)
            Cs[(wv * 16 + lq * 4 + r) * 132 + c * 16 + lr] = acc[c][r];
    __syncthreads();

    // coalesced bf16 writeback: thread -> node = t>>2, seg = t&3 (32 cols each)
    int nd = t >> 2, seg = t & 3;
    if (node0 + nd < n) {
        const float* src = &Cs[nd * 132 + seg * 32];
        u32 o[16];
        #pragma unroll
        for (int i = 0; i < 16; ++i) o[i] = packbf2(src[2 * i], src[2 * i + 1]);
        uint4* dst = (uint4*)(C + (size_t)(node0 + nd) * NH + seg * 32);
        dst[0] = make_uint4(o[0],  o[1],  o[2],  o[3]);
        dst[1] = make_uint4(o[4],  o[5],  o[6],  o[7]);
        dst[2] = make_uint4(o[8],  o[9],  o[10], o[11]);
        dst[3] = make_uint4(o[12], o[13], o[14], o[15]);
    }
}

// ---------------- fused CSR aggregate (bf16 gather) + self-loop + bias + relu ----------------
// one node per 64-lane wave; lane covers 2 features (bf16x2 = 1 dword); unroll x4.

__global__ __launch_bounds__(256) void gcn_aggregate(const u16* __restrict__ tmpb,
                                                     const uint2* __restrict__ edges,
                                                     const int* __restrict__ offs,
                                                     const int* __restrict__ deg,
                                                     const float* __restrict__ dinv,
                                                     const float* __restrict__ bias,
                                                     u16* __restrict__ outb, int n) {
    int wv = threadIdx.x >> 6;
    int l  = threadIdx.x & 63;
    int node = blockIdx.x * 4 + wv;
    if (node >= n) return;
    int start = offs[node];
    int end   = start + deg[node];
    const u32* rows = (const u32*)tmpb;   // 64 dwords per node row

    float a0 = 0.f, a1 = 0.f;
    int k = start;
    for (; k + 4 <= end; k += 4) {
        uint2 e0 = edges[k], e1 = edges[k + 1], e2 = edges[k + 2], e3 = edges[k + 3];
        u32 g0 = rows[(size_t)e0.x * 64 + l];
        u32 g1 = rows[(size_t)e1.x * 64 + l];
        u32 g2 = rows[(size_t)e2.x * 64 + l];
        u32 g3 = rows[(size_t)e3.x * 64 + l];
        float n0 = __uint_as_float(e0.y), n1 = __uint_as_float(e1.y);
        float n2 = __uint_as_float(e2.y), n3 = __uint_as_float(e3.y);
        a0 += n0 * bflo(g0) + n1 * bflo(g1) + n2 * bflo(g2) + n3 * bflo(g3);
        a1 += n0 * bfhi(g0) + n1 * bfhi(g1) + n2 * bfhi(g2) + n3 * bfhi(g3);
    }
    for (; k < end; ++k) {
        uint2 e = edges[k];
        u32 g = rows[(size_t)e.x * 64 + l];
        float nv = __uint_as_float(e.y);
        a0 += nv * bflo(g); a1 += nv * bfhi(g);
    }
    // self loop
    u32 gs = rows[(size_t)node * 64 + l];
    float di = dinv[node]; float d2 = di * di;
    a0 += d2 * bflo(gs); a1 += d2 * bfhi(gs);
    float2 bb = *(const float2*)&bias[l * 2];
    a0 = fmaxf(a0 + bb.x, 0.f);
    a1 = fmaxf(a1 + bb.y, 0.f);
    ((u32*)outb)[(size_t)node * 64 + l] = packbf2(a0, a1);
}

// ---------------- fused mean-pool + final FC (bf16 h input) ----------------

__global__ __launch_bounds__(256) void pool_fc(const u16* __restrict__ h,
                                               const int* __restrict__ batch,
                                               const float* __restrict__ Wfc,
                                               const float* __restrict__ bfc,
                                               float* __restrict__ out, int n) {
    int g = blockIdx.x;
    int tid = threadIdx.x;
    int j = tid & 127;
    int half = tid >> 7;

    int lo = 0, hi = n;
    while (lo < hi) { int m = (lo + hi) >> 1; if (batch[m] < g) lo = m + 1; else hi = m; }
    int start = lo;
    hi = n;
    while (lo < hi) { int m = (lo + hi) >> 1; if (batch[m] < g + 1) lo = m + 1; else hi = m; }
    int end = lo;

    float acc = 0.f;
    for (int i = start + half; i < end; i += 2)
        acc += __uint_as_float((u32)h[(size_t)i * NH + j] << 16);

    __shared__ float sum[NH];
    __shared__ float pr[NH];
    if (half == 0) sum[j] = acc;
    __syncthreads();
    if (half == 1) sum[j] += acc;
    __syncthreads();
    float inv = 1.0f / fmaxf((float)(end - start), 1.0f);
    if (half == 0) pr[j] = sum[j] * inv;
    __syncthreads();

    float o = bfc[tid];
    #pragma unroll 8
    for (int k = 0; k < NH; ++k) o += pr[k] * Wfc[(size_t)k * NO + tid];
    out[(size_t)g * NO + tid] = o;
}

// ---------------- launch ----------------

extern "C" void kernel_launch(void* const* d_in, const int* in_sizes, int n_in,
                              void* d_out, int out_size, void* d_ws, size_t ws_size,
                              hipStream_t stream) {
    const float* x   = (const float*)d_in[0];
    const float* W1  = (const float*)d_in[1];
    const float* b1  = (const float*)d_in[2];
    const float* W2  = (const float*)d_in[3];
    const float* b2  = (const float*)d_in[4];
    const float* W3  = (const float*)d_in[5];
    const float* b3  = (const float*)d_in[6];
    const float* Wfc = (const float*)d_in[7];
    const float* bfc = (const float*)d_in[8];
    const int*   ei  = (const int*)d_in[9];
    const int*   bat = (const int*)d_in[10];
    float* out = (float*)d_out;

    const int N = in_sizes[0] / NF;
    const int E = in_sizes[9] / 2;
    const int* rowp = ei;
    const int* colp = ei + E;

    // workspace layout
    char* w = (char*)d_ws;
    uint2* edges = (uint2*)w;                    w += (size_t)E * 8;
    u16* hA   = (u16*)w;                         w += (size_t)N * NH * 2;
    u16* hB   = (u16*)w;                         w += (size_t)N * NH * 2;
    u16* tmpb = (u16*)w;                         w += (size_t)N * NH * 2;
    u16* Wt1  = (u16*)w;                         w += NF * NH * 2;
    u16* Wt2  = (u16*)w;                         w += NF * NH * 2;
    u16* Wt3  = (u16*)w;                         w += NF * NH * 2;
    float* dinv = (float*)w;                     w += (size_t)N * 4;
    int* degc   = (int*)w;                       w += (size_t)N * 4;
    int* offs   = (int*)w;                       w += (size_t)N * 4;
    int* cursor = (int*)w;                       w += (size_t)N * 4;
    int* partials = (int*)w;                     w += 512 * 4;

    const int TB = 256;
    int gE = (E + TB - 1) / TB;
    int gN = (N + TB - 1) / TB;
    int gGemm = (N + 63) / 64;
    int gAgg  = (N + 3) / 4;
    int nScanBlocks = (N + 255) / 256;   // <= 512

    // ---- CSR build ----
    hipMemsetAsync(degc, 0, (size_t)N * sizeof(int), stream);
    hipMemsetAsync(cursor, 0, (size_t)N * sizeof(int), stream);
    hist_kernel<<<gE, TB, 0, stream>>>(colp, E, degc);
    dinv_kernel<<<gN, TB, 0, stream>>>(degc, dinv, N);
    scan1<<<nScanBlocks, 256, 0, stream>>>(degc, N, offs, partials);
    scan2<<<1, 512, 0, stream>>>(partials, nScanBlocks);
    scan3<<<gN, TB, 0, stream>>>(offs, partials, N);
    build_csr<<<gE, TB, 0, stream>>>(rowp, colp, dinv, offs, cursor, edges, E);

    // ---- casts ----
    long total4 = (long)N * NF / 4;
    cast_x_kernel<<<(int)((total4 + 255) / 256), TB, 0, stream>>>(x, hA, total4);
    cast_w_t<<<64, TB, 0, stream>>>(W1, Wt1);
    cast_w_t<<<64, TB, 0, stream>>>(W2, Wt2);
    cast_w_t<<<64, TB, 0, stream>>>(W3, Wt3);

    // ---- layer 1 ----
    gemm_mfma<<<gGemm, TB, 0, stream>>>(hA, Wt1, tmpb, N);
    gcn_aggregate<<<gAgg, TB, 0, stream>>>(tmpb, edges, offs, degc, dinv, b1, hB, N);

    // ---- layer 2 ----
    gemm_mfma<<<gGemm, TB, 0, stream>>>(hB, Wt2, tmpb, N);
    gcn_aggregate<<<gAgg, TB, 0, stream>>>(tmpb, edges, offs, degc, dinv, b2, hA, N);

    // ---- layer 3 ----
    gemm_mfma<<<gGemm, TB, 0, stream>>>(hA, Wt3, tmpb, N);
    gcn_aggregate<<<gAgg, TB, 0, stream>>>(tmpb, edges, offs, degc, dinv, b3, hB, N);

    // ---- fused pool + fc ----
    pool_fc<<<NG, 256, 0, stream>>>(hB, bat, Wfc, bfc, out, N);
}

// Round 6
// 569.716 us; speedup vs baseline: 5.3494x; 1.0771x over previous
//
#include <hip/hip_runtime.h>

#define NF 128
#define NH 128
#define NO 256
#define NG 256

typedef unsigned int   u32;
typedef unsigned short u16;
typedef __attribute__((ext_vector_type(8))) short short8;
typedef __attribute__((ext_vector_type(4))) float floatx4;

__device__ __forceinline__ float bflo(u32 g) { return __uint_as_float(g << 16); }
__device__ __forceinline__ float bfhi(u32 g) { return __uint_as_float(g & 0xffff0000u); }
__device__ __forceinline__ u16 f2bf(float x) {
    u32 u = __float_as_uint(x);
    u += 0x7fffu + ((u >> 16) & 1u);
    return (u16)(u >> 16);
}
__device__ __forceinline__ u32 packbf2(float x, float y) {
    u32 ux = __float_as_uint(x); ux += 0x7fffu + ((ux >> 16) & 1u);
    u32 uy = __float_as_uint(y); uy += 0x7fffu + ((uy >> 16) & 1u);
    return (ux >> 16) | (uy & 0xffff0000u);
}

// ---------------- degree histogram ----------------

__global__ void hist_kernel(const int* __restrict__ col, int E, int* __restrict__ deg) {
    int e = blockIdx.x * blockDim.x + threadIdx.x;
    if (e < E) atomicAdd(&deg[col[e]], 1);
}

// ---------------- scan (+dinv fused) ----------------

__global__ void scan1(const int* __restrict__ deg, int n, int* __restrict__ offs,
                      int* __restrict__ partials, float* __restrict__ dinv) {
    __shared__ int sh[256];
    int tid = threadIdx.x;
    int i = blockIdx.x * 256 + tid;
    int v = (i < n) ? deg[i] : 0;
    if (i < n) dinv[i] = rsqrtf((float)v + 1.0f);
    sh[tid] = v; __syncthreads();
    for (int d = 1; d < 256; d <<= 1) {
        int t = (tid >= d) ? sh[tid - d] : 0;
        __syncthreads();
        sh[tid] += t;
        __syncthreads();
    }
    if (i < n) offs[i] = sh[tid] - v;
    if (tid == 255) partials[blockIdx.x] = sh[255];
}

__global__ void scan2(int* __restrict__ partials, int nb) {
    __shared__ int sh[512];
    int tid = threadIdx.x;
    int v = (tid < nb) ? partials[tid] : 0;
    sh[tid] = v; __syncthreads();
    for (int d = 1; d < 512; d <<= 1) {
        int t = (tid >= d) ? sh[tid - d] : 0;
        __syncthreads();
        sh[tid] += t;
        __syncthreads();
    }
    if (tid < nb) partials[tid] = sh[tid] - v;
}

// finalize offs; also init coarse-bucket global cursors gcur[b] = offs[b*512]
__global__ void scan3_gcur(int* __restrict__ offs, const int* __restrict__ partials,
                           int* __restrict__ gcur, int n) {
    int i = blockIdx.x * blockDim.x + threadIdx.x;
    if (i < n) {
        int v = offs[i] + partials[i >> 8];
        offs[i] = v;
        if ((i & 511) == 0) gcur[i >> 9] = v;
    }
}

// ---------------- phase 1: coarse binning (bucket = col >> 9) ----------------
// 4096 edges per 256-thread WG; LDS-staged, coalesced bucket-contiguous flush.
// packed record: row (17 bits) | (col & 511) << 17

__global__ __launch_bounds__(256) void bin_coarse(const int* __restrict__ row,
                                                  const int* __restrict__ col,
                                                  int* __restrict__ gcur,
                                                  u32* __restrict__ coarse, int E) {
    __shared__ u32 cnt[256];     // counts -> exclusive scan (bucket starts)
    __shared__ u32 lcur[256];
    __shared__ u32 gbase[256];
    __shared__ u32 sc[256];
    __shared__ u32 packed[4096];
    int t = threadIdx.x;
    int base = blockIdx.x * 4096;
    cnt[t] = 0;
    __syncthreads();

    u32 rv[16], cv[16];
    #pragma unroll
    for (int i = 0; i < 16; ++i) {
        int e = base + i * 256 + t;
        if (e < E) {
            rv[i] = (u32)row[e];
            cv[i] = (u32)col[e];
            atomicAdd(&cnt[cv[i] >> 9], 1u);
        }
    }
    __syncthreads();
    u32 own = cnt[t];
    sc[t] = own; __syncthreads();
    for (int d = 1; d < 256; d <<= 1) {
        u32 x = (t >= d) ? sc[t - d] : 0;
        __syncthreads();
        sc[t] += x;
        __syncthreads();
    }
    u32 excl = sc[t] - own;
    u32 total = sc[255];
    if (own > 0) gbase[t] = (u32)atomicAdd(&gcur[t], (int)own);
    cnt[t]  = excl;     // bucket start within packed
    lcur[t] = excl;
    __syncthreads();

    #pragma unroll
    for (int i = 0; i < 16; ++i) {
        int e = base + i * 256 + t;
        if (e < E) {
            u32 p = atomicAdd(&lcur[cv[i] >> 9], 1u);
            packed[p] = rv[i] | ((cv[i] & 511u) << 17);
        }
    }
    __syncthreads();

    for (u32 i = t; i < total; i += 256) {
        u32 lo = 0, hi = 255;          // max b with cnt[b] <= i
        while (lo < hi) { u32 mid = (lo + hi + 1) >> 1; if (cnt[mid] <= i) lo = mid; else hi = mid - 1; }
        coarse[gbase[lo] + (i - cnt[lo])] = packed[i];
    }
}

// ---------------- phase 2: fine scatter within 64KB bucket windows ----------------

__global__ __launch_bounds__(256) void scatter_fine(const u32* __restrict__ coarse,
                                                    const int* __restrict__ offs,
                                                    int* __restrict__ cursor,
                                                    const float* __restrict__ dinv,
                                                    uint2* __restrict__ edges,
                                                    int N, int E) {
    int b    = blockIdx.x >> 2;
    int part = blockIdx.x & 3;
    int lo_node = b << 9;
    if (lo_node >= N) return;
    int hi_node = min(lo_node + 512, N);
    int start = offs[lo_node];
    int end   = (hi_node < N) ? offs[hi_node] : E;
    int seg = end - start;
    int chunk = (seg + 3) >> 2;
    int s0 = start + part * chunk;
    int s1 = min(s0 + chunk, end);
    for (int i = s0 + (int)threadIdx.x; i < s1; i += 256) {
        u32 pk = coarse[i];
        u32 r = pk & 0x1ffffu;
        u32 c = (u32)lo_node + (pk >> 17);
        int p = offs[c] + atomicAdd(&cursor[c], 1);
        uint2 v; v.x = r; v.y = __float_as_uint(dinv[r] * dinv[c]);
        edges[p] = v;
    }
}

// ---------------- casts ----------------

__global__ void cast_x_kernel(const float* __restrict__ x, u16* __restrict__ xb, long total4) {
    long i = (long)blockIdx.x * 256 + threadIdx.x;
    if (i < total4) {
        float4 v = ((const float4*)x)[i];
        ushort4 o; o.x = f2bf(v.x); o.y = f2bf(v.y); o.z = f2bf(v.z); o.w = f2bf(v.w);
        ((ushort4*)xb)[i] = o;
    }
}

// three W[k][col] f32 -> Wt[col][k] bf16 (128x128 each), one kernel
__global__ void cast_w_t3(const float* __restrict__ W1, const float* __restrict__ W2,
                          const float* __restrict__ W3, u16* __restrict__ Wt1,
                          u16* __restrict__ Wt2, u16* __restrict__ Wt3) {
    int idx = blockIdx.x * 256 + threadIdx.x;   // 0 .. 3*16384
    int w = idx >> 14;
    int r = idx & 16383;
    const float* W = (w == 0) ? W1 : (w == 1) ? W2 : W3;
    u16* Wt = (w == 0) ? Wt1 : (w == 1) ? Wt2 : Wt3;
    int k = r >> 7, c = r & 127;
    Wt[c * NF + k] = f2bf(W[r]);
}

// ---------------- MFMA GEMM: C[n x 128] = A[n x 128] @ W[128 x 128], bf16 in/out ----------------

__global__ __launch_bounds__(256) void gemm_mfma(const u16* __restrict__ A,
                                                 const u16* __restrict__ Wtg,
                                                 u16* __restrict__ C, int n) {
    __shared__ u16 As[64 * 136];
    __shared__ u16 Wt[128 * 136];
    int t = threadIdx.x;
    int node0 = blockIdx.x * 64;

    const uint4* Ag = (const uint4*)A;
    #pragma unroll
    for (int i = 0; i < 4; ++i) {
        int idx = t + 256 * i;
        int nd = idx >> 4, q = idx & 15;
        uint4 v = make_uint4(0, 0, 0, 0);
        if (node0 + nd < n) v = Ag[(size_t)(node0 + nd) * 16 + q];
        *(uint4*)&As[nd * 136 + q * 8] = v;
    }
    const uint4* Wg = (const uint4*)Wtg;
    #pragma unroll
    for (int i = 0; i < 8; ++i) {
        int idx = t + 256 * i;
        int cc = idx >> 4, q = idx & 15;
        *(uint4*)&Wt[cc * 136 + q * 8] = Wg[cc * 16 + q];
    }
    __syncthreads();

    int wv = t >> 6;
    int l  = t & 63;
    int lr = l & 15;
    int lq = l >> 4;

    floatx4 acc[8];
    #pragma unroll
    for (int c = 0; c < 8; ++c) acc[c] = (floatx4){0.f, 0.f, 0.f, 0.f};

    #pragma unroll
    for (int kk = 0; kk < 4; ++kk) {
        short8 af = *(const short8*)&As[(wv * 16 + lr) * 136 + kk * 32 + lq * 8];
        #pragma unroll
        for (int c = 0; c < 8; ++c) {
            short8 bf = *(const short8*)&Wt[(c * 16 + lr) * 136 + kk * 32 + lq * 8];
            acc[c] = __builtin_amdgcn_mfma_f32_16x16x32_bf16(af, bf, acc[c], 0, 0, 0);
        }
    }
    __syncthreads();

    float* Cs = (float*)Wt;   // 64 x 132 f32
    #pragma unroll
    for (int c = 0; c < 8; ++c)
        #pragma unroll
        for (int r = 0; r < 4; ++r)
            Cs[(wv * 16 + lq * 4 + r) * 132 + c * 16 + lr] = acc[c][r];
    __syncthreads();

    int nd = t >> 2, seg = t & 3;
    if (node0 + nd < n) {
        const float* src = &Cs[nd * 132 + seg * 32];
        u32 o[16];
        #pragma unroll
        for (int i = 0; i < 16; ++i) o[i] = packbf2(src[2 * i], src[2 * i + 1]);
        uint4* dst = (uint4*)(C + (size_t)(node0 + nd) * NH + seg * 32);
        dst[0] = make_uint4(o[0],  o[1],  o[2],  o[3]);
        dst[1] = make_uint4(o[4],  o[5],  o[6],  o[7]);
        dst[2] = make_uint4(o[8],  o[9],  o[10], o[11]);
        dst[3] = make_uint4(o[12], o[13], o[14], o[15]);
    }
}

// ---------------- fused CSR aggregate (bf16 gather) + self-loop + bias + relu ----------------

__global__ __launch_bounds__(256) void gcn_aggregate(const u16* __restrict__ tmpb,
                                                     const uint2* __restrict__ edges,
                                                     const int* __restrict__ offs,
                                                     const int* __restrict__ deg,
                                                     const float* __restrict__ dinv,
                                                     const float* __restrict__ bias,
                                                     u16* __restrict__ outb, int n) {
    int wv = threadIdx.x >> 6;
    int l  = threadIdx.x & 63;
    int node = blockIdx.x * 4 + wv;
    if (node >= n) return;
    int start = offs[node];
    int end   = start + deg[node];
    const u32* rows = (const u32*)tmpb;

    float a0 = 0.f, a1 = 0.f;
    int k = start;
    for (; k + 4 <= end; k += 4) {
        uint2 e0 = edges[k], e1 = edges[k + 1], e2 = edges[k + 2], e3 = edges[k + 3];
        u32 g0 = rows[(size_t)e0.x * 64 + l];
        u32 g1 = rows[(size_t)e1.x * 64 + l];
        u32 g2 = rows[(size_t)e2.x * 64 + l];
        u32 g3 = rows[(size_t)e3.x * 64 + l];
        float n0 = __uint_as_float(e0.y), n1 = __uint_as_float(e1.y);
        float n2 = __uint_as_float(e2.y), n3 = __uint_as_float(e3.y);
        a0 += n0 * bflo(g0) + n1 * bflo(g1) + n2 * bflo(g2) + n3 * bflo(g3);
        a1 += n0 * bfhi(g0) + n1 * bfhi(g1) + n2 * bfhi(g2) + n3 * bfhi(g3);
    }
    for (; k < end; ++k) {
        uint2 e = edges[k];
        u32 g = rows[(size_t)e.x * 64 + l];
        float nv = __uint_as_float(e.y);
        a0 += nv * bflo(g); a1 += nv * bfhi(g);
    }
    u32 gs = rows[(size_t)node * 64 + l];
    float di = dinv[node]; float d2 = di * di;
    a0 += d2 * bflo(gs); a1 += d2 * bfhi(gs);
    float2 bb = *(const float2*)&bias[l * 2];
    a0 = fmaxf(a0 + bb.x, 0.f);
    a1 = fmaxf(a1 + bb.y, 0.f);
    ((u32*)outb)[(size_t)node * 64 + l] = packbf2(a0, a1);
}

// ---------------- fused mean-pool + final FC (bf16 h input, x4 ILP) ----------------

__global__ __launch_bounds__(256) void pool_fc(const u16* __restrict__ h,
                                               const int* __restrict__ batch,
                                               const float* __restrict__ Wfc,
                                               const float* __restrict__ bfc,
                                               float* __restrict__ out, int n) {
    int g = blockIdx.x;
    int tid = threadIdx.x;
    int j = tid & 127;
    int half = tid >> 7;

    int lo = 0, hi = n;
    while (lo < hi) { int m = (lo + hi) >> 1; if (batch[m] < g) lo = m + 1; else hi = m; }
    int start = lo;
    hi = n;
    while (lo < hi) { int m = (lo + hi) >> 1; if (batch[m] < g + 1) lo = m + 1; else hi = m; }
    int end = lo;

    float a0 = 0.f, a1 = 0.f, a2 = 0.f, a3 = 0.f;
    int i = start + half;
    for (; i + 6 < end; i += 8) {
        u32 v0 = (u32)h[(size_t)i * NH + j];
        u32 v1 = (u32)h[(size_t)(i + 2) * NH + j];
        u32 v2 = (u32)h[(size_t)(i + 4) * NH + j];
        u32 v3 = (u32)h[(size_t)(i + 6) * NH + j];
        a0 += __uint_as_float(v0 << 16);
        a1 += __uint_as_float(v1 << 16);
        a2 += __uint_as_float(v2 << 16);
        a3 += __uint_as_float(v3 << 16);
    }
    for (; i < end; i += 2)
        a0 += __uint_as_float((u32)h[(size_t)i * NH + j] << 16);
    float acc = (a0 + a1) + (a2 + a3);

    __shared__ float sum[NH];
    __shared__ float pr[NH];
    if (half == 0) sum[j] = acc;
    __syncthreads();
    if (half == 1) sum[j] += acc;
    __syncthreads();
    float inv = 1.0f / fmaxf((float)(end - start), 1.0f);
    if (half == 0) pr[j] = sum[j] * inv;
    __syncthreads();

    float o = bfc[tid];
    #pragma unroll 8
    for (int k = 0; k < NH; ++k) o += pr[k] * Wfc[(size_t)k * NO + tid];
    out[(size_t)g * NO + tid] = o;
}

// ---------------- launch ----------------

extern "C" void kernel_launch(void* const* d_in, const int* in_sizes, int n_in,
                              void* d_out, int out_size, void* d_ws, size_t ws_size,
                              hipStream_t stream) {
    const float* x   = (const float*)d_in[0];
    const float* W1  = (const float*)d_in[1];
    const float* b1  = (const float*)d_in[2];
    const float* W2  = (const float*)d_in[3];
    const float* b2  = (const float*)d_in[4];
    const float* W3  = (const float*)d_in[5];
    const float* b3  = (const float*)d_in[6];
    const float* Wfc = (const float*)d_in[7];
    const float* bfc = (const float*)d_in[8];
    const int*   ei  = (const int*)d_in[9];
    const int*   bat = (const int*)d_in[10];
    float* out = (float*)d_out;

    const int N = in_sizes[0] / NF;
    const int E = in_sizes[9] / 2;
    const int* rowp = ei;
    const int* colp = ei + E;

    // workspace layout
    char* w = (char*)d_ws;
    uint2* edges = (uint2*)w;                    w += (size_t)E * 8;
    u32* coarse  = (u32*)w;                      w += (size_t)E * 4;
    u16* hA   = (u16*)w;                         w += (size_t)N * NH * 2;
    u16* hB   = (u16*)w;                         w += (size_t)N * NH * 2;
    u16* tmpb = (u16*)w;                         w += (size_t)N * NH * 2;
    u16* Wt1  = (u16*)w;                         w += NF * NH * 2;
    u16* Wt2  = (u16*)w;                         w += NF * NH * 2;
    u16* Wt3  = (u16*)w;                         w += NF * NH * 2;
    float* dinv = (float*)w;                     w += (size_t)N * 4;
    int* degc   = (int*)w;                       w += (size_t)N * 4;
    int* cursor = (int*)w;                       w += (size_t)N * 4;   // adjacent to degc (one memset)
    int* offs   = (int*)w;                       w += (size_t)N * 4;
    int* partials = (int*)w;                     w += 512 * 4;
    int* gcur   = (int*)w;                       w += 256 * 4;

    const int TB = 256;
    int gE = (E + TB - 1) / TB;
    int gN = (N + TB - 1) / TB;
    int gGemm = (N + 63) / 64;
    int gAgg  = (N + 3) / 4;
    int nScanBlocks = (N + 255) / 256;   // <= 512
    int NB = (N + 511) >> 9;             // coarse buckets (<=256)
    int gBin = (E + 4095) / 4096;

    // ---- CSR build ----
    hipMemsetAsync(degc, 0, 2 * (size_t)N * sizeof(int), stream);   // degc + cursor
    hist_kernel<<<gE, TB, 0, stream>>>(colp, E, degc);
    scan1<<<nScanBlocks, 256, 0, stream>>>(degc, N, offs, partials, dinv);
    scan2<<<1, 512, 0, stream>>>(partials, nScanBlocks);
    scan3_gcur<<<gN, TB, 0, stream>>>(offs, partials, gcur, N);
    bin_coarse<<<gBin, TB, 0, stream>>>(rowp, colp, gcur, coarse, E);
    scatter_fine<<<NB * 4, TB, 0, stream>>>(coarse, offs, cursor, dinv, edges, N, E);

    // ---- casts ----
    long total4 = (long)N * NF / 4;
    cast_x_kernel<<<(int)((total4 + 255) / 256), TB, 0, stream>>>(x, hA, total4);
    cast_w_t3<<<192, TB, 0, stream>>>(W1, W2, W3, Wt1, Wt2, Wt3);

    // ---- layer 1 ----
    gemm_mfma<<<gGemm, TB, 0, stream>>>(hA, Wt1, tmpb, N);
    gcn_aggregate<<<gAgg, TB, 0, stream>>>(tmpb, edges, offs, degc, dinv, b1, hB, N);

    // ---- layer 2 ----
    gemm_mfma<<<gGemm, TB, 0, stream>>>(hB, Wt2, tmpb, N);
    gcn_aggregate<<<gAgg, TB, 0, stream>>>(tmpb, edges, offs, degc, dinv, b2, hA, N);

    // ---- layer 3 ----
    gemm_mfma<<<gGemm, TB, 0, stream>>>(hA, Wt3, tmpb, N);
    gcn_aggregate<<<gAgg, TB, 0, stream>>>(tmpb, edges, offs, degc, dinv, b3, hB, N);

    // ---- fused pool + fc ----
    pool_fc<<<NG, 256, 0, stream>>>(hB, bat, Wfc, bfc, out, N);
}

// Round 7
// 543.233 us; speedup vs baseline: 5.6102x; 1.0488x over previous
//
#include <hip/hip_runtime.h>

#define NF 128
#define NH 128
#define NO 256
#define NG 256

typedef unsigned int   u32;
typedef unsigned short u16;
typedef __attribute__((ext_vector_type(8))) short short8;
typedef __attribute__((ext_vector_type(4))) float floatx4;

__device__ __forceinline__ float bflo(u32 g) { return __uint_as_float(g << 16); }
__device__ __forceinline__ float bfhi(u32 g) { return __uint_as_float(g & 0xffff0000u); }
__device__ __forceinline__ u16 f2bf(float x) {
    u32 u = __float_as_uint(x);
    u += 0x7fffu + ((u >> 16) & 1u);
    return (u16)(u >> 16);
}
__device__ __forceinline__ u32 packbf2(float x, float y) {
    u32 ux = __float_as_uint(x); ux += 0x7fffu + ((ux >> 16) & 1u);
    u32 uy = __float_as_uint(y); uy += 0x7fffu + ((uy >> 16) & 1u);
    return (ux >> 16) | (uy & 0xffff0000u);
}

// ---------------- degree histogram ----------------

__global__ void hist_kernel(const int* __restrict__ col, int E, int* __restrict__ deg) {
    int e = blockIdx.x * blockDim.x + threadIdx.x;
    if (e < E) atomicAdd(&deg[col[e]], 1);
}

// ---------------- scan (+dinv fused) ----------------

__global__ void scan1(const int* __restrict__ deg, int n, int* __restrict__ offs,
                      int* __restrict__ partials, float* __restrict__ dinv) {
    __shared__ int sh[256];
    int tid = threadIdx.x;
    int i = blockIdx.x * 256 + tid;
    int v = (i < n) ? deg[i] : 0;
    if (i < n) dinv[i] = rsqrtf((float)v + 1.0f);
    sh[tid] = v; __syncthreads();
    for (int d = 1; d < 256; d <<= 1) {
        int t = (tid >= d) ? sh[tid - d] : 0;
        __syncthreads();
        sh[tid] += t;
        __syncthreads();
    }
    if (i < n) offs[i] = sh[tid] - v;
    if (tid == 255) partials[blockIdx.x] = sh[255];
}

__global__ void scan2(int* __restrict__ partials, int nb) {
    __shared__ int sh[512];
    int tid = threadIdx.x;
    int v = (tid < nb) ? partials[tid] : 0;
    sh[tid] = v; __syncthreads();
    for (int d = 1; d < 512; d <<= 1) {
        int t = (tid >= d) ? sh[tid - d] : 0;
        __syncthreads();
        sh[tid] += t;
        __syncthreads();
    }
    if (tid < nb) partials[tid] = sh[tid] - v;
}

// finalize offs; also init coarse-bucket global cursors gcur[b] = offs[b*512]
__global__ void scan3_gcur(int* __restrict__ offs, const int* __restrict__ partials,
                           int* __restrict__ gcur, int n) {
    int i = blockIdx.x * blockDim.x + threadIdx.x;
    if (i < n) {
        int v = offs[i] + partials[i >> 8];
        offs[i] = v;
        if ((i & 511) == 0) gcur[i >> 9] = v;
    }
}

// ---------------- phase 1: coarse binning (bucket = col >> 9) ----------------
// packed record: row (17 bits) | (col & 511) << 17

__global__ __launch_bounds__(256) void bin_coarse(const int* __restrict__ row,
                                                  const int* __restrict__ col,
                                                  int* __restrict__ gcur,
                                                  u32* __restrict__ coarse, int E) {
    __shared__ u32 cnt[256];
    __shared__ u32 lcur[256];
    __shared__ u32 gbase[256];
    __shared__ u32 sc[256];
    __shared__ u32 packed[4096];
    int t = threadIdx.x;
    int base = blockIdx.x * 4096;
    cnt[t] = 0;
    __syncthreads();

    u32 rv[16], cv[16];
    #pragma unroll
    for (int i = 0; i < 16; ++i) {
        int e = base + i * 256 + t;
        if (e < E) {
            rv[i] = (u32)row[e];
            cv[i] = (u32)col[e];
            atomicAdd(&cnt[cv[i] >> 9], 1u);
        }
    }
    __syncthreads();
    u32 own = cnt[t];
    sc[t] = own; __syncthreads();
    for (int d = 1; d < 256; d <<= 1) {
        u32 x = (t >= d) ? sc[t - d] : 0;
        __syncthreads();
        sc[t] += x;
        __syncthreads();
    }
    u32 excl = sc[t] - own;
    u32 total = sc[255];
    if (own > 0) gbase[t] = (u32)atomicAdd(&gcur[t], (int)own);
    cnt[t]  = excl;
    lcur[t] = excl;
    __syncthreads();

    #pragma unroll
    for (int i = 0; i < 16; ++i) {
        int e = base + i * 256 + t;
        if (e < E) {
            u32 p = atomicAdd(&lcur[cv[i] >> 9], 1u);
            packed[p] = rv[i] | ((cv[i] & 511u) << 17);
        }
    }
    __syncthreads();

    for (u32 i = t; i < total; i += 256) {
        u32 lo = 0, hi = 255;
        while (lo < hi) { u32 mid = (lo + hi + 1) >> 1; if (cnt[mid] <= i) lo = mid; else hi = mid - 1; }
        coarse[gbase[lo] + (i - cnt[lo])] = packed[i];
    }
}

// ---------------- phase 2: fine scatter (4B records, 32KB windows) ----------------

__global__ __launch_bounds__(256) void scatter_fine(const u32* __restrict__ coarse,
                                                    const int* __restrict__ offs,
                                                    int* __restrict__ cursor,
                                                    u32* __restrict__ srcs,
                                                    int N, int E) {
    int b    = blockIdx.x >> 2;
    int part = blockIdx.x & 3;
    int lo_node = b << 9;
    if (lo_node >= N) return;
    int hi_node = min(lo_node + 512, N);
    int start = offs[lo_node];
    int end   = (hi_node < N) ? offs[hi_node] : E;
    int seg = end - start;
    int chunk = (seg + 3) >> 2;
    int s0 = start + part * chunk;
    int s1 = min(s0 + chunk, end);
    for (int i = s0 + (int)threadIdx.x; i < s1; i += 256) {
        u32 pk = coarse[i];
        u32 r = pk & 0x1ffffu;
        u32 c = (u32)lo_node + (pk >> 17);
        int p = offs[c] + atomicAdd(&cursor[c], 1);
        srcs[p] = r;
    }
}

// ---------------- casts ----------------

__global__ void cast_x_kernel(const float* __restrict__ x, u16* __restrict__ xb, long total4) {
    long i = (long)blockIdx.x * 256 + threadIdx.x;
    if (i < total4) {
        float4 v = ((const float4*)x)[i];
        ushort4 o; o.x = f2bf(v.x); o.y = f2bf(v.y); o.z = f2bf(v.z); o.w = f2bf(v.w);
        ((ushort4*)xb)[i] = o;
    }
}

__global__ void cast_w_t3(const float* __restrict__ W1, const float* __restrict__ W2,
                          const float* __restrict__ W3, u16* __restrict__ Wt1,
                          u16* __restrict__ Wt2, u16* __restrict__ Wt3) {
    int idx = blockIdx.x * 256 + threadIdx.x;
    int w = idx >> 14;
    int r = idx & 16383;
    const float* W = (w == 0) ? W1 : (w == 1) ? W2 : W3;
    u16* Wt = (w == 0) ? Wt1 : (w == 1) ? Wt2 : Wt3;
    int k = r >> 7, c = r & 127;
    Wt[c * NF + k] = f2bf(W[r]);
}

// ---------------- MFMA GEMM + dinv row-scale epilogue ----------------
// writes g[node] = dinv[node] * (A[node] @ W)  (bf16)

__global__ __launch_bounds__(256) void gemm_mfma(const u16* __restrict__ A,
                                                 const u16* __restrict__ Wtg,
                                                 const float* __restrict__ dinv,
                                                 u16* __restrict__ C, int n) {
    __shared__ u16 As[64 * 136];
    __shared__ u16 Wt[128 * 136];
    int t = threadIdx.x;
    int node0 = blockIdx.x * 64;

    const uint4* Ag = (const uint4*)A;
    #pragma unroll
    for (int i = 0; i < 4; ++i) {
        int idx = t + 256 * i;
        int nd = idx >> 4, q = idx & 15;
        uint4 v = make_uint4(0, 0, 0, 0);
        if (node0 + nd < n) v = Ag[(size_t)(node0 + nd) * 16 + q];
        *(uint4*)&As[nd * 136 + q * 8] = v;
    }
    const uint4* Wg = (const uint4*)Wtg;
    #pragma unroll
    for (int i = 0; i < 8; ++i) {
        int idx = t + 256 * i;
        int cc = idx >> 4, q = idx & 15;
        *(uint4*)&Wt[cc * 136 + q * 8] = Wg[cc * 16 + q];
    }
    __syncthreads();

    int wv = t >> 6;
    int l  = t & 63;
    int lr = l & 15;
    int lq = l >> 4;

    floatx4 acc[8];
    #pragma unroll
    for (int c = 0; c < 8; ++c) acc[c] = (floatx4){0.f, 0.f, 0.f, 0.f};

    #pragma unroll
    for (int kk = 0; kk < 4; ++kk) {
        short8 af = *(const short8*)&As[(wv * 16 + lr) * 136 + kk * 32 + lq * 8];
        #pragma unroll
        for (int c = 0; c < 8; ++c) {
            short8 bf = *(const short8*)&Wt[(c * 16 + lr) * 136 + kk * 32 + lq * 8];
            acc[c] = __builtin_amdgcn_mfma_f32_16x16x32_bf16(af, bf, acc[c], 0, 0, 0);
        }
    }
    __syncthreads();

    float* Cs = (float*)Wt;   // 64 x 132 f32
    #pragma unroll
    for (int c = 0; c < 8; ++c)
        #pragma unroll
        for (int r = 0; r < 4; ++r)
            Cs[(wv * 16 + lq * 4 + r) * 132 + c * 16 + lr] = acc[c][r];
    __syncthreads();

    int nd = t >> 2, seg = t & 3;
    if (node0 + nd < n) {
        float di = dinv[node0 + nd];
        const float* src = &Cs[nd * 132 + seg * 32];
        u32 o[16];
        #pragma unroll
        for (int i = 0; i < 16; ++i) o[i] = packbf2(di * src[2 * i], di * src[2 * i + 1]);
        uint4* dst = (uint4*)(C + (size_t)(node0 + nd) * NH + seg * 32);
        dst[0] = make_uint4(o[0],  o[1],  o[2],  o[3]);
        dst[1] = make_uint4(o[4],  o[5],  o[6],  o[7]);
        dst[2] = make_uint4(o[8],  o[9],  o[10], o[11]);
        dst[3] = make_uint4(o[12], o[13], o[14], o[15]);
    }
}

// ---------------- fused aggregate: out = relu(dinv*(sum g[src] + g[self]) + b) ----------------
// one node per wave; chunk-16 gather for MLP.

__global__ __launch_bounds__(256) void gcn_aggregate(const u16* __restrict__ gtab,
                                                     const u32* __restrict__ srcs,
                                                     const int* __restrict__ offs,
                                                     const int* __restrict__ deg,
                                                     const float* __restrict__ dinv,
                                                     const float* __restrict__ bias,
                                                     u16* __restrict__ outb, int n) {
    int wv = threadIdx.x >> 6;
    int l  = threadIdx.x & 63;
    int node = blockIdx.x * 4 + wv;
    if (node >= n) return;
    int start = offs[node];
    int end   = start + deg[node];
    const u32* rows = (const u32*)gtab;

    float a0 = 0.f, a1 = 0.f;
    int k = start;
    for (; k + 16 <= end; k += 16) {
        u32 gv[16];
        #pragma unroll
        for (int i = 0; i < 16; ++i) {
            u32 s = srcs[k + i];
            gv[i] = rows[(size_t)s * 64 + l];
        }
        #pragma unroll
        for (int i = 0; i < 16; ++i) { a0 += bflo(gv[i]); a1 += bfhi(gv[i]); }
    }
    for (; k + 4 <= end; k += 4) {
        u32 s0 = srcs[k], s1 = srcs[k + 1], s2 = srcs[k + 2], s3 = srcs[k + 3];
        u32 g0 = rows[(size_t)s0 * 64 + l];
        u32 g1 = rows[(size_t)s1 * 64 + l];
        u32 g2 = rows[(size_t)s2 * 64 + l];
        u32 g3 = rows[(size_t)s3 * 64 + l];
        a0 += bflo(g0) + bflo(g1) + bflo(g2) + bflo(g3);
        a1 += bfhi(g0) + bfhi(g1) + bfhi(g2) + bfhi(g3);
    }
    for (; k < end; ++k) {
        u32 g = rows[(size_t)srcs[k] * 64 + l];
        a0 += bflo(g); a1 += bfhi(g);
    }
    // self loop: + g[node], then scale by dinv[node]
    u32 gs = rows[(size_t)node * 64 + l];
    a0 += bflo(gs); a1 += bfhi(gs);
    float di = dinv[node];
    float2 bb = *(const float2*)&bias[l * 2];
    a0 = fmaxf(di * a0 + bb.x, 0.f);
    a1 = fmaxf(di * a1 + bb.y, 0.f);
    ((u32*)outb)[(size_t)node * 64 + l] = packbf2(a0, a1);
}

// ---------------- fused mean-pool + final FC ----------------

__global__ __launch_bounds__(256) void pool_fc(const u16* __restrict__ h,
                                               const int* __restrict__ batch,
                                               const float* __restrict__ Wfc,
                                               const float* __restrict__ bfc,
                                               float* __restrict__ out, int n) {
    int g = blockIdx.x;
    int tid = threadIdx.x;
    int j = tid & 127;
    int half = tid >> 7;

    int lo = 0, hi = n;
    while (lo < hi) { int m = (lo + hi) >> 1; if (batch[m] < g) lo = m + 1; else hi = m; }
    int start = lo;
    hi = n;
    while (lo < hi) { int m = (lo + hi) >> 1; if (batch[m] < g + 1) lo = m + 1; else hi = m; }
    int end = lo;

    float a0 = 0.f, a1 = 0.f, a2 = 0.f, a3 = 0.f;
    int i = start + half;
    for (; i + 6 < end; i += 8) {
        u32 v0 = (u32)h[(size_t)i * NH + j];
        u32 v1 = (u32)h[(size_t)(i + 2) * NH + j];
        u32 v2 = (u32)h[(size_t)(i + 4) * NH + j];
        u32 v3 = (u32)h[(size_t)(i + 6) * NH + j];
        a0 += __uint_as_float(v0 << 16);
        a1 += __uint_as_float(v1 << 16);
        a2 += __uint_as_float(v2 << 16);
        a3 += __uint_as_float(v3 << 16);
    }
    for (; i < end; i += 2)
        a0 += __uint_as_float((u32)h[(size_t)i * NH + j] << 16);
    float acc = (a0 + a1) + (a2 + a3);

    __shared__ float sum[NH];
    __shared__ float pr[NH];
    if (half == 0) sum[j] = acc;
    __syncthreads();
    if (half == 1) sum[j] += acc;
    __syncthreads();
    float inv = 1.0f / fmaxf((float)(end - start), 1.0f);
    if (half == 0) pr[j] = sum[j] * inv;
    __syncthreads();

    float o = bfc[tid];
    #pragma unroll 8
    for (int k = 0; k < NH; ++k) o += pr[k] * Wfc[(size_t)k * NO + tid];
    out[(size_t)g * NO + tid] = o;
}

// ---------------- launch ----------------

extern "C" void kernel_launch(void* const* d_in, const int* in_sizes, int n_in,
                              void* d_out, int out_size, void* d_ws, size_t ws_size,
                              hipStream_t stream) {
    const float* x   = (const float*)d_in[0];
    const float* W1  = (const float*)d_in[1];
    const float* b1  = (const float*)d_in[2];
    const float* W2  = (const float*)d_in[3];
    const float* b2  = (const float*)d_in[4];
    const float* W3  = (const float*)d_in[5];
    const float* b3  = (const float*)d_in[6];
    const float* Wfc = (const float*)d_in[7];
    const float* bfc = (const float*)d_in[8];
    const int*   ei  = (const int*)d_in[9];
    const int*   bat = (const int*)d_in[10];
    float* out = (float*)d_out;

    const int N = in_sizes[0] / NF;
    const int E = in_sizes[9] / 2;
    const int* rowp = ei;
    const int* colp = ei + E;

    // workspace layout
    char* w = (char*)d_ws;
    u32* srcs    = (u32*)w;                      w += (size_t)E * 4;
    u32* coarse  = (u32*)w;                      w += (size_t)E * 4;
    u16* hA   = (u16*)w;                         w += (size_t)N * NH * 2;
    u16* hB   = (u16*)w;                         w += (size_t)N * NH * 2;
    u16* tmpb = (u16*)w;                         w += (size_t)N * NH * 2;
    u16* Wt1  = (u16*)w;                         w += NF * NH * 2;
    u16* Wt2  = (u16*)w;                         w += NF * NH * 2;
    u16* Wt3  = (u16*)w;                         w += NF * NH * 2;
    float* dinv = (float*)w;                     w += (size_t)N * 4;
    int* degc   = (int*)w;                       w += (size_t)N * 4;
    int* cursor = (int*)w;                       w += (size_t)N * 4;   // adjacent to degc (one memset)
    int* offs   = (int*)w;                       w += (size_t)N * 4;
    int* partials = (int*)w;                     w += 512 * 4;
    int* gcur   = (int*)w;                       w += 256 * 4;

    const int TB = 256;
    int gE = (E + TB - 1) / TB;
    int gN = (N + TB - 1) / TB;
    int gGemm = (N + 63) / 64;
    int gAgg  = (N + 3) / 4;
    int nScanBlocks = (N + 255) / 256;   // <= 512
    int NB = (N + 511) >> 9;             // coarse buckets (<=256)
    int gBin = (E + 4095) / 4096;

    // ---- CSR build ----
    hipMemsetAsync(degc, 0, 2 * (size_t)N * sizeof(int), stream);   // degc + cursor
    hist_kernel<<<gE, TB, 0, stream>>>(colp, E, degc);
    scan1<<<nScanBlocks, 256, 0, stream>>>(degc, N, offs, partials, dinv);
    scan2<<<1, 512, 0, stream>>>(partials, nScanBlocks);
    scan3_gcur<<<gN, TB, 0, stream>>>(offs, partials, gcur, N);
    bin_coarse<<<gBin, TB, 0, stream>>>(rowp, colp, gcur, coarse, E);
    scatter_fine<<<NB * 4, TB, 0, stream>>>(coarse, offs, cursor, srcs, N, E);

    // ---- casts ----
    long total4 = (long)N * NF / 4;
    cast_x_kernel<<<(int)((total4 + 255) / 256), TB, 0, stream>>>(x, hA, total4);
    cast_w_t3<<<192, TB, 0, stream>>>(W1, W2, W3, Wt1, Wt2, Wt3);

    // ---- layer 1 ----
    gemm_mfma<<<gGemm, TB, 0, stream>>>(hA, Wt1, dinv, tmpb, N);
    gcn_aggregate<<<gAgg, TB, 0, stream>>>(tmpb, srcs, offs, degc, dinv, b1, hB, N);

    // ---- layer 2 ----
    gemm_mfma<<<gGemm, TB, 0, stream>>>(hB, Wt2, dinv, tmpb, N);
    gcn_aggregate<<<gAgg, TB, 0, stream>>>(tmpb, srcs, offs, degc, dinv, b2, hA, N);

    // ---- layer 3 ----
    gemm_mfma<<<gGemm, TB, 0, stream>>>(hA, Wt3, dinv, tmpb, N);
    gcn_aggregate<<<gAgg, TB, 0, stream>>>(tmpb, srcs, offs, degc, dinv, b3, hB, N);

    // ---- fused pool + fc ----
    pool_fc<<<NG, 256, 0, stream>>>(hB, bat, Wfc, bfc, out, N);
}